// Round 5
// baseline (280.486 us; speedup 1.0000x reference)
//
#include <hip/hip_runtime.h>

// All tensors float32. Math structure exploited:
//  - softmax over axis of size 1 == 1.0 -> attn all-ones, Wa/ba dead.
//  - weighted = row-sum of tanh(agg), broadcast over COLUMNS (N==D quirk).
//  - lig_p = nf@Wl.T + const  ->  x0[h,i,j] = PL[i,h] + PR[j,h] + c[h]
//  - conv1/2/3 fully fused, x0 generated on the fly (no 128MB tensor).
//  - gnn GEMM and convs on f16 MFMA, f32 accumulate.
//  - conv LDS is GRANULE-MAJOR (plane = 8-ci granule): tap reads are one base
//    register + compile-time offset immediates; contiguous per quarter-wave
//    -> no bank conflicts, minimal VALU addressing.

typedef _Float16 half8 __attribute__((ext_vector_type(8)));
typedef _Float16 half4 __attribute__((ext_vector_type(4)));
typedef float    f32x4 __attribute__((ext_vector_type(4)));

__device__ __forceinline__ short f2h_bits(float f){
    _Float16 h = (_Float16)f;          // RNE
    return __builtin_bit_cast(short, h);
}
__device__ __forceinline__ half8 pack2(const float4& x, const float4& y){
    half8 r;
    r[0] = (_Float16)x.x; r[1] = (_Float16)x.y;
    r[2] = (_Float16)x.z; r[3] = (_Float16)x.w;
    r[4] = (_Float16)y.x; r[5] = (_Float16)y.y;
    r[6] = (_Float16)y.z; r[7] = (_Float16)y.w;
    return r;
}
__device__ __forceinline__ half4 pack4(const float4& x){
    half4 r;
    r[0] = (_Float16)x.x; r[1] = (_Float16)x.y;
    r[2] = (_Float16)x.z; r[3] = (_Float16)x.w;
    return r;
}

// ---------------------------------------------------------------------------
// K1 (MFMA): agg = tanh([nf|ef]@[Wn|We].T + bn + be); per-block row-sums over
// its 64 d-columns -> part[cx][dblk][row]. BM=BN=64, BK=64, 256 thr (4 waves,
// wave-tile 32x32), grid (16,16,2). LDS tiles f16, granule XOR swizzle.
// ---------------------------------------------------------------------------
__global__ __launch_bounds__(256) void gnn_kernel(
    const float* __restrict__ lig_nf, const float* __restrict__ lig_ef,
    const float* __restrict__ rec_nf, const float* __restrict__ rec_ef,
    const float* __restrict__ Wn, const float* __restrict__ We,
    const float* __restrict__ bn, const float* __restrict__ be,
    float* __restrict__ part)   // [2][16][1024]
{
    __shared__ __attribute__((aligned(16))) short As[64 * 64];
    __shared__ __attribute__((aligned(16))) short Bs[64 * 64];
    __shared__ float red[64][2];

    const int t  = threadIdx.x;
    const int cx = blockIdx.z;
    const float* A0 = cx ? rec_nf : lig_nf;
    const float* A1 = cx ? rec_ef : lig_ef;
    const int j0 = blockIdx.x * 64;
    const int d0 = blockIdx.y * 64;

    const int wid  = t >> 6;
    const int wm   = wid >> 1, wn = wid & 1;
    const int lane = t & 63;
    const int lr   = lane & 15;   // A: row, B: col, C: col
    const int lg   = lane >> 4;   // k-granule / C row group

    f32x4 acc[2][2];
    #pragma unroll
    for (int m = 0; m < 2; ++m)
        #pragma unroll
        for (int n = 0; n < 2; ++n)
            acc[m][n] = (f32x4){0.f, 0.f, 0.f, 0.f};

    const int srow   = t >> 2;    // staging row 0..63
    const int schunk = t & 3;     // 16-float chunk of the 64-wide K slab
    const int sswz   = srow & 7;

    for (int kb = 0; kb < 2048; kb += 64){
        const float* Asrc = (kb < 1024) ? A0 : A1;
        const float* Bsrc = (kb < 1024) ? Wn : We;
        const int kcol = (kb & 1023) + schunk * 16;
        float4 av[4], bv[4];
        const float* ap = Asrc + (size_t)(j0 + srow) * 1024 + kcol;
        const float* bp = Bsrc + (size_t)(d0 + srow) * 1024 + kcol;
        #pragma unroll
        for (int q = 0; q < 4; ++q){
            av[q] = *reinterpret_cast<const float4*>(ap + q * 4);
            bv[q] = *reinterpret_cast<const float4*>(bp + q * 4);
        }
        __syncthreads();   // previous iter's LDS reads done
        const int g0 = ((schunk * 2)     ^ sswz) * 8;
        const int g1 = ((schunk * 2 + 1) ^ sswz) * 8;
        *reinterpret_cast<half8*>(&As[srow * 64 + g0]) = pack2(av[0], av[1]);
        *reinterpret_cast<half8*>(&As[srow * 64 + g1]) = pack2(av[2], av[3]);
        *reinterpret_cast<half8*>(&Bs[srow * 64 + g0]) = pack2(bv[0], bv[1]);
        *reinterpret_cast<half8*>(&Bs[srow * 64 + g1]) = pack2(bv[2], bv[3]);
        __syncthreads();

        #pragma unroll
        for (int ks = 0; ks < 2; ++ks){
            half8 Af[2], Bf[2];
            #pragma unroll
            for (int m = 0; m < 2; ++m){
                int row = wm * 32 + m * 16 + lr;
                int g   = ((ks * 4 + lg) ^ (row & 7)) * 8;
                Af[m] = *reinterpret_cast<const half8*>(&As[row * 64 + g]);
            }
            #pragma unroll
            for (int n = 0; n < 2; ++n){
                int col = wn * 32 + n * 16 + lr;
                int g   = ((ks * 4 + lg) ^ (col & 7)) * 8;
                Bf[n] = *reinterpret_cast<const half8*>(&Bs[col * 64 + g]);
            }
            #pragma unroll
            for (int m = 0; m < 2; ++m)
                #pragma unroll
                for (int n = 0; n < 2; ++n)
                    acc[m][n] = __builtin_amdgcn_mfma_f32_16x16x32_f16(
                        Af[m], Bf[n], acc[m][n], 0, 0, 0);
        }
    }

    // epilogue: bias + tanh + reduce over the block's 64 d-columns
    float rowsum[2][4];
    #pragma unroll
    for (int m = 0; m < 2; ++m)
        #pragma unroll
        for (int jj = 0; jj < 4; ++jj) rowsum[m][jj] = 0.f;
    #pragma unroll
    for (int n = 0; n < 2; ++n){
        int d = d0 + wn * 32 + n * 16 + lr;
        float bias = bn[d] + be[d];
        #pragma unroll
        for (int m = 0; m < 2; ++m)
            #pragma unroll
            for (int jj = 0; jj < 4; ++jj)
                rowsum[m][jj] += tanhf(acc[m][n][jj] + bias);
    }
    #pragma unroll
    for (int mask = 1; mask < 16; mask <<= 1)
        #pragma unroll
        for (int m = 0; m < 2; ++m)
            #pragma unroll
            for (int jj = 0; jj < 4; ++jj)
                rowsum[m][jj] += __shfl_xor(rowsum[m][jj], mask);
    __syncthreads();
    if (lr == 0){
        #pragma unroll
        for (int m = 0; m < 2; ++m)
            #pragma unroll
            for (int jj = 0; jj < 4; ++jj)
                red[wm * 32 + m * 16 + lg * 4 + jj][wn] = rowsum[m][jj];
    }
    __syncthreads();
    if (t < 64)
        part[(size_t)cx * 16384 + (size_t)blockIdx.y * 1024 + j0 + t]
            = red[t][0] + red[t][1];
}

// ---------------------------------------------------------------------------
// K2a: PL[i,h] = sum_j nf[i,j]*Wl[h,j]; PR analog. grid (128,2), block 256
// ---------------------------------------------------------------------------
__global__ __launch_bounds__(256) void proj_kernel(
    const float* __restrict__ lig_nf, const float* __restrict__ rec_nf,
    const float* __restrict__ W_hopi, float* __restrict__ PL, float* __restrict__ PR)
{
    const int t  = threadIdx.x;
    const int cx = blockIdx.y;
    const float* nf = cx ? rec_nf : lig_nf;
    const float* W  = W_hopi + (cx ? 1024 : 0);
    float* outp     = cx ? PR : PL;
    const int h = t & 31;
    const int i = blockIdx.x * 8 + (t >> 5);
    const float* nrow = nf + (size_t)i * 1024;
    const float* wrow = W + (size_t)h * 2048;
    float s0 = 0.f, s1 = 0.f;
    #pragma unroll 4
    for (int j = 0; j < 1024; j += 8){
        float4 a0 = *reinterpret_cast<const float4*>(nrow + j);
        float4 b0 = *reinterpret_cast<const float4*>(wrow + j);
        float4 a1 = *reinterpret_cast<const float4*>(nrow + j + 4);
        float4 b1 = *reinterpret_cast<const float4*>(wrow + j + 4);
        s0 = fmaf(a0.x, b0.x, s0); s0 = fmaf(a0.y, b0.y, s0);
        s0 = fmaf(a0.z, b0.z, s0); s0 = fmaf(a0.w, b0.w, s0);
        s1 = fmaf(a1.x, b1.x, s1); s1 = fmaf(a1.y, b1.y, s1);
        s1 = fmaf(a1.z, b1.z, s1); s1 = fmaf(a1.w, b1.w, s1);
    }
    outp[(size_t)i * 32 + h] = s0 + s1;
}

// ---------------------------------------------------------------------------
// K2b: w[j] = block-sum of part; c[h] = b_hopi[h] + wL.Wl[h] + wR.Wr[h]
// ---------------------------------------------------------------------------
__global__ __launch_bounds__(256) void cvec_kernel(
    const float* __restrict__ W_hopi, const float* __restrict__ b_hopi,
    const float* __restrict__ part, float* __restrict__ cvec)
{
    __shared__ float ws_l[1024];
    __shared__ float ws_r[1024];
    __shared__ float red[256];
    const int t = threadIdx.x;
    for (int j = t; j < 1024; j += 256){
        float sl = 0.f, sr = 0.f;
        #pragma unroll
        for (int b = 0; b < 16; ++b){
            sl += part[b * 1024 + j];
            sr += part[16384 + b * 1024 + j];
        }
        ws_l[j] = sl; ws_r[j] = sr;
    }
    __syncthreads();
    const int h = t & 31;
    const int seg = t >> 5;
    float s = 0.f;
    for (int j = seg * 128; j < seg * 128 + 128; ++j){
        s = fmaf(ws_l[j], W_hopi[(size_t)h * 2048 + j], s);
        s = fmaf(ws_r[j], W_hopi[(size_t)h * 2048 + 1024 + j], s);
    }
    red[t] = s;
    __syncthreads();
    if (t < 32){
        float tot = b_hopi[t];
        #pragma unroll
        for (int g = 0; g < 8; ++g) tot += red[g * 32 + t];
        cvec[t] = tot;
    }
}

// ---------------------------------------------------------------------------
// K3: fused conv1+relu -> conv2+relu -> conv3 on f16 MFMA, granule-major LDS.
// Plane strides (shorts): XS_P=3216, YS_P=2608, WB_P=2320 (pads de-alias
// quarter-waves). LDS = 65,152 B -> 2 blocks/CU. block 512, grid 64x64.
// ---------------------------------------------------------------------------
#define XS_P 3216
#define YS_P 2608
#define WB_P 2320

__global__ __launch_bounds__(512) void conv_kernel(
    const float* __restrict__ PL, const float* __restrict__ PR,
    const float* __restrict__ cvec,
    const float* __restrict__ w1, const float* __restrict__ b1,
    const float* __restrict__ w2, const float* __restrict__ b2,
    const float* __restrict__ w3, const float* __restrict__ b3,
    float* __restrict__ outp)
{
    __shared__ __attribute__((aligned(16))) short xs[4 * XS_P];
    __shared__ __attribute__((aligned(16))) short ys[4 * YS_P];
    __shared__ __attribute__((aligned(16))) short wB[4 * WB_P];

    const int t    = threadIdx.x;
    const int oy0  = blockIdx.y * 16;
    const int ox0  = blockIdx.x * 16;
    const int wid  = t >> 6;
    const int lane = t & 63;
    const int lr   = lane & 15;
    const int lg   = lane >> 4;

    // ---- stage x0 tile: 400 pixels x 32 ci, granule-major ----
    {
        const int cp  = (t & 7) * 4;      // ci quad
        const int grp = t >> 3;           // 64 pixels per pass
        #pragma unroll
        for (int pass = 0; pass < 7; ++pass){
            int pp = grp + pass * 64;
            if (pp < 400){
                int ry = pp / 20, rx = pp - ry * 20;
                int a = oy0 - 2 + ry, b = ox0 - 2 + rx;
                float4 v = make_float4(0.f, 0.f, 0.f, 0.f);
                if (a >= 0 && a < 1024 && b >= 0 && b < 1024){
                    float4 pl = *reinterpret_cast<const float4*>(PL + a * 32 + cp);
                    float4 pr = *reinterpret_cast<const float4*>(PR + b * 32 + cp);
                    float4 cv = *reinterpret_cast<const float4*>(cvec + cp);
                    v = make_float4(pl.x + pr.x + cv.x, pl.y + pr.y + cv.y,
                                    pl.z + pr.z + cv.z, pl.w + pr.w + cv.w);
                }
                *reinterpret_cast<half4*>(
                    &xs[(cp >> 3) * XS_P + pp * 8 + (cp & 7)]) = pack4(v);
            }
        }
    }
    // ---- stage conv1 weights: wB[ci>>3][tap*32+co][ci&7] ----
    #pragma unroll
    for (int k = 0; k < 18; ++k){
        int u = t + 512 * k;
        int cil = u & 7;
        int co  = (u >> 3) & 31;
        int top = u >> 8;                 // 0..35
        int tap = top % 9;
        int ci  = (top / 9) * 8 + cil;
        wB[(ci >> 3) * WB_P + (tap * 32 + co) * 8 + cil] =
            f2h_bits(w1[co * 288 + ci * 9 + tap]);
    }
    __syncthreads();

    // ================= conv1: 324 outputs (18x18) =========
    {
        half8 Bf[2][9];
        float bias[2];
        #pragma unroll
        for (int n = 0; n < 2; ++n){
            int co = n * 16 + lr;
            bias[n] = b1[co];
            #pragma unroll
            for (int tap = 0; tap < 9; ++tap)
                Bf[n][tap] = *reinterpret_cast<const half8*>(
                    &wB[lg * WB_P + (tap * 32 + co) * 8]);
        }
        for (int s = wid; s < 21; s += 8){
            int praw = s * 16 + lr;
            int p  = praw > 323 ? 323 : praw;
            int ry = p / 18;
            int rx = p - ry * 18;
            const short* abase = &xs[lg * XS_P + (ry * 20 + rx) * 8];
            f32x4 acc0 = {0.f, 0.f, 0.f, 0.f};
            f32x4 acc1 = {0.f, 0.f, 0.f, 0.f};
            #pragma unroll
            for (int tap = 0; tap < 9; ++tap){
                const int dy = tap / 3, dx = tap - (tap / 3) * 3;
                half8 A = *reinterpret_cast<const half8*>(abase + (dy * 20 + dx) * 8);
                acc0 = __builtin_amdgcn_mfma_f32_16x16x32_f16(A, Bf[0][tap], acc0, 0, 0, 0);
                acc1 = __builtin_amdgcn_mfma_f32_16x16x32_f16(A, Bf[1][tap], acc1, 0, 0, 0);
            }
            #pragma unroll
            for (int j = 0; j < 4; ++j){
                int po = s * 16 + lg * 4 + j;
                if (po < 324){
                    int ryo = po / 18;
                    int rxo = po - ryo * 18;
                    int gy = oy0 - 1 + ryo, gx = ox0 - 1 + rxo;
                    bool ok = (gy >= 0) & (gy < 1024) & (gx >= 0) & (gx < 1024);
                    float v0 = ok ? fmaxf(acc0[j] + bias[0], 0.f) : 0.f;
                    float v1 = ok ? fmaxf(acc1[j] + bias[1], 0.f) : 0.f;
                    ys[(lr >> 3) * YS_P + po * 8 + (lr & 7)]       = f2h_bits(v0);
                    ys[((lr >> 3) + 2) * YS_P + po * 8 + (lr & 7)] = f2h_bits(v1);
                }
            }
        }
    }
    __syncthreads();
    // ---- restage weights for conv2 ----
    #pragma unroll
    for (int k = 0; k < 18; ++k){
        int u = t + 512 * k;
        int cil = u & 7;
        int co  = (u >> 3) & 31;
        int top = u >> 8;
        int tap = top % 9;
        int ci  = (top / 9) * 8 + cil;
        wB[(ci >> 3) * WB_P + (tap * 32 + co) * 8 + cil] =
            f2h_bits(w2[co * 288 + ci * 9 + tap]);
    }
    __syncthreads();

    // ================= conv2 + conv3: 256 outputs =========
    {
        half8 Bf[2][9];
        float bias[2], w3v[2];
        #pragma unroll
        for (int n = 0; n < 2; ++n){
            int co = n * 16 + lr;
            bias[n] = b2[co];
            w3v[n]  = w3[co];
            #pragma unroll
            for (int tap = 0; tap < 9; ++tap)
                Bf[n][tap] = *reinterpret_cast<const half8*>(
                    &wB[lg * WB_P + (tap * 32 + co) * 8]);
        }
        const float b3v = b3[0];
        for (int s = wid; s < 16; s += 8){
            int p  = s * 16 + lr;
            int ry = p >> 4;
            int rx = p & 15;
            const short* ybase = &ys[lg * YS_P + (ry * 18 + rx) * 8];
            f32x4 acc0 = {0.f, 0.f, 0.f, 0.f};
            f32x4 acc1 = {0.f, 0.f, 0.f, 0.f};
            #pragma unroll
            for (int tap = 0; tap < 9; ++tap){
                const int dy = tap / 3, dx = tap - (tap / 3) * 3;
                half8 A = *reinterpret_cast<const half8*>(ybase + (dy * 18 + dx) * 8);
                acc0 = __builtin_amdgcn_mfma_f32_16x16x32_f16(A, Bf[0][tap], acc0, 0, 0, 0);
                acc1 = __builtin_amdgcn_mfma_f32_16x16x32_f16(A, Bf[1][tap], acc1, 0, 0, 0);
            }
            float part[4];
            #pragma unroll
            for (int j = 0; j < 4; ++j)
                part[j] = w3v[0] * fmaxf(acc0[j] + bias[0], 0.f)
                        + w3v[1] * fmaxf(acc1[j] + bias[1], 0.f);
            #pragma unroll
            for (int m = 1; m < 16; m <<= 1)
                #pragma unroll
                for (int j = 0; j < 4; ++j)
                    part[j] += __shfl_xor(part[j], m);
            if (lr == 0){
                float4 o = make_float4(part[0] + b3v, part[1] + b3v,
                                       part[2] + b3v, part[3] + b3v);
                *reinterpret_cast<float4*>(outp + (size_t)(oy0 + s) * 1024 + ox0 + lg * 4) = o;
            }
        }
    }
}

// ---------------------------------------------------------------------------
extern "C" void kernel_launch(void* const* d_in, const int* in_sizes, int n_in,
                              void* d_out, int out_size, void* d_ws, size_t ws_size,
                              hipStream_t stream)
{
    const float* lig_nf = (const float*)d_in[0];
    const float* lig_ef = (const float*)d_in[1];
    const float* rec_nf = (const float*)d_in[3];
    const float* rec_ef = (const float*)d_in[4];
    const float* Wn     = (const float*)d_in[6];
    const float* bn     = (const float*)d_in[7];
    const float* We     = (const float*)d_in[8];
    const float* be     = (const float*)d_in[9];
    const float* W_hopi = (const float*)d_in[12];
    const float* b_hopi = (const float*)d_in[13];
    const float* w1     = (const float*)d_in[14];
    const float* b1     = (const float*)d_in[15];
    const float* w2     = (const float*)d_in[16];
    const float* b2     = (const float*)d_in[17];
    const float* w3     = (const float*)d_in[18];
    const float* b3     = (const float*)d_in[19];
    float* outp = (float*)d_out;

    float* part = (float*)d_ws;                               // [2][16][1024]
    float* PL   = (float*)((char*)d_ws + 131072);
    float* PR   = (float*)((char*)d_ws + 262144);
    float* cvec = (float*)((char*)d_ws + 393216);

    dim3 g1(16, 16, 2);
    gnn_kernel<<<g1, 256, 0, stream>>>(lig_nf, lig_ef, rec_nf, rec_ef,
                                       Wn, We, bn, be, part);
    dim3 g2(128, 2);
    proj_kernel<<<g2, 256, 0, stream>>>(lig_nf, rec_nf, W_hopi, PL, PR);
    cvec_kernel<<<1, 256, 0, stream>>>(W_hopi, b_hopi, part, cvec);
    dim3 g3(64, 64);
    conv_kernel<<<g3, 512, 0, stream>>>(PL, PR, cvec, w1, b1, w2, b2, w3, b3, outp);
}